// Round 1
// 989.294 us; speedup vs baseline: 1.0964x; 1.0964x over previous
//
#include <hip/hip_runtime.h>

// MoE experts: N=8192, K=2, E=8, H=2048, I=1408.
// Round 4: split gemm1 (pure GEMM N=2816) + swiglu pass; both GEMMs use
// double-buffered LDS with cross-tile global_load_lds prefetch, raw s_barrier +
// manual vmcnt(0) (T3-minimal schedule); flattened exact grid with bijective
// XCD swizzle; outs aliases gupT (ws 264 MB).

#define N_TOK 8192
#define TOPK  2
#define NEXP  8
#define HD    2048
#define ID    1408
#define NK    (N_TOK * TOPK)   // 16384
#define MAXRT 136              // max row-tiles: NK/128 + NEXP ceil slack

typedef __bf16 bf16x8 __attribute__((ext_vector_type(8)));
typedef float  f32x4  __attribute__((ext_vector_type(4)));

__device__ __forceinline__ float b2f(unsigned short u) {
    union { unsigned int i; float f; } v; v.i = ((unsigned int)u) << 16; return v.f;
}
__device__ __forceinline__ unsigned short f2b(float f) {
    union { float f; unsigned int i; } v; v.f = f;
    unsigned int x = v.i;
    return (unsigned short)((x + 0x7fffu + ((x >> 16) & 1u)) >> 16);   // RNE
}

// async global->LDS, 16B per lane; dest = wave-uniform base + lane*16
__device__ __forceinline__ void glds16(const void* g, void* l) {
    __builtin_amdgcn_global_load_lds(
        (const __attribute__((address_space(1))) unsigned int*)g,
        (__attribute__((address_space(3))) unsigned int*)l,
        16, 0, 0);
}

// ---------------- dtype probe: 1 = fp32 storage, 0 = bf16 storage ----------------

__global__ void probe_k(const unsigned short* __restrict__ xu, int* __restrict__ mode) {
    __shared__ int c;
    if (threadIdx.x == 0) c = 0;
    __syncthreads();
    float a = fabsf(b2f(xu[threadIdx.x * 2]));
    int sane = (a > 1e-4f && a < 100.f) ? 1 : 0;
    atomicAdd(&c, sane);
    __syncthreads();
    if (threadIdx.x == 0) mode[0] = (c < 512) ? 1 : 0;
}

// ---------------- x -> bf16 ----------------

__global__ void convert_x(const void* __restrict__ x, unsigned short* __restrict__ xb,
                          const int* __restrict__ mode) {
    int gid = blockIdx.x * 256 + threadIdx.x;      // N*H/8 threads
    size_t o = (size_t)gid * 8;
    if (mode[0]) {
        const float* f = (const float*)x + o;
        float4 f0 = *(const float4*)f;
        float4 f1 = *(const float4*)(f + 4);
        uint4 v;
        v.x = f2b(f0.x) | ((unsigned int)f2b(f0.y) << 16);
        v.y = f2b(f0.z) | ((unsigned int)f2b(f0.w) << 16);
        v.z = f2b(f1.x) | ((unsigned int)f2b(f1.y) << 16);
        v.w = f2b(f1.z) | ((unsigned int)f2b(f1.w) << 16);
        *(uint4*)(xb + o) = v;
    } else {
        *(uint4*)(xb + o) = *(const uint4*)((const unsigned short*)x + o);
    }
}

// ---------------- routing ----------------

__global__ void init_k(int* cnt, int* fill) {
    int t = threadIdx.x;
    if (t < NEXP) { cnt[t] = 0; fill[t] = 0; }
}

__global__ void route_count(const int* __restrict__ idx, int* __restrict__ cnt) {
    int s = blockIdx.x * 256 + threadIdx.x;
    if (s < NK) atomicAdd(&cnt[idx[s]], 1);
}

__global__ void route_scan(const int* __restrict__ cnt, int* __restrict__ base,
                           int* __restrict__ tb) {
    if (threadIdx.x == 0) {
        int acc = 0, tacc = 0;
        for (int e = 0; e < NEXP; e++) {
            base[e] = acc; tb[e] = tacc;
            acc += cnt[e]; tacc += (cnt[e] + 127) >> 7;
        }
        base[NEXP] = acc; tb[NEXP] = tacc;
    }
}

__global__ void route_scatter(const int* __restrict__ idx,
                              const int* __restrict__ base,
                              int* __restrict__ fill,
                              int* __restrict__ tok,
                              int* __restrict__ inv) {
    int s = blockIdx.x * 256 + threadIdx.x;
    if (s < NK) {
        int e = idx[s];
        int p = base[e] + atomicAdd(&fill[e], 1);
        tok[p] = s >> 1;           // TOPK == 2
        inv[s] = p;
    }
}

// ---------------- weight transpose: per-expert [R][C] (fp32 or bf16) -> [C][R] bf16 ----

__global__ void transpose_k(const void* __restrict__ in, unsigned short* __restrict__ out,
                            int R, int C, const int* __restrict__ mode) {
    __shared__ float tile[64][65];
    bool fp32m = (mode[0] != 0);
    int e  = blockIdx.z;
    int c0 = blockIdx.x * 64, r0 = blockIdx.y * 64;
    int t = threadIdx.x;
    if (fp32m) {
        const float* inp = (const float*)in + (size_t)e * R * C;
        for (int i = 0; i < 16; i++) {
            int lin = t + i * 256;
            int r = lin >> 6, c = lin & 63;
            tile[r][c] = inp[(size_t)(r0 + r) * C + c0 + c];
        }
    } else {
        const unsigned int* inp = (const unsigned int*)in + (size_t)e * R * (C >> 1);
        for (int i = 0; i < 8; i++) {
            int lin = t + i * 256;
            int r = lin >> 5, cu = lin & 31;
            unsigned int v = inp[(size_t)(r0 + r) * (C >> 1) + (c0 >> 1) + cu];
            tile[r][2 * cu]     = b2f((unsigned short)(v & 0xffffu));
            tile[r][2 * cu + 1] = b2f((unsigned short)(v >> 16));
        }
    }
    __syncthreads();
    unsigned int* outp = (unsigned int*)out + (size_t)e * C * (R >> 1);
    for (int i = 0; i < 8; i++) {
        int lin = t + i * 256;
        int c = lin >> 5, ru = lin & 31;
        unsigned int lo = f2b(tile[2 * ru][c]);
        unsigned int hi = f2b(tile[2 * ru + 1][c]);
        outp[(size_t)(c0 + c) * (R >> 1) + (r0 >> 1) + ru] = lo | (hi << 16);
    }
}

// LDS swizzle: element (row r, k-chunk c8) lives at 16B-slot  r*8 + (c8 ^ (r&7)).
// - DMA write: wave writes slots [wbase, wbase+64) contiguously; global source
//   address carries the inverse permutation (chunk (s&7)^(r&7)).
// - Frag read b128: 16 consecutive rows x fixed kc per quad -> covers all 32
//   banks exactly twice = conflict-free (verified: SQ_LDS_BANK_CONFLICT == 0).

// ---------------- grouped GEMM, 128x128 tile, BK=64, double-buffered prefetch ----
// A: [rows][LDA] bf16 (row via tok[] gather if GATHER), B: [E][ND][KD] bf16 (transposed),
// C: [NK][ND] bf16.  Grid: 1D, MAXRT * (ND/128) blocks, exact tiles via tb[].

template<int KD, int ND, int LDA, bool GATHER>
__launch_bounds__(256, 2)
__global__ void gemm_k(const unsigned short* __restrict__ A,
                       const unsigned short* __restrict__ B,
                       const int* __restrict__ base,
                       const int* __restrict__ tb,
                       const int* __restrict__ tok,
                       unsigned short* __restrict__ C) {
    const int CT = ND / 128;
    // bijective XCD swizzle on flattened block id (T1, m204 formula)
    int G = gridDim.x;
    int orig = blockIdx.x;
    int q8 = G >> 3, r8 = G & 7, xcd = orig & 7, lin = orig >> 3;
    int wgid = (xcd < r8 ? xcd * (q8 + 1) : r8 * (q8 + 1) + (xcd - r8) * q8) + lin;
    int ct  = wgid % CT;          // ct-minor: consecutive ids share the A panel
    int rtf = wgid / CT;
    if (rtf >= tb[NEXP]) return;
    int e = 0;
    while (tb[e + 1] <= rtf) e++;
    int row0 = base[e] + (rtf - tb[e]) * 128;
    int rend = base[e + 1];

    __shared__ unsigned short As[2][128 * 64];
    __shared__ unsigned short Bs[2][128 * 64];

    int tid  = threadIdx.x;
    int lane = tid & 63;
    int wave = tid >> 6;
    int wm = wave & 1, wn = wave >> 1;
    int l15 = lane & 15, qq = lane >> 4;

    const unsigned short* bptr = B + (size_t)e * ND * KD + (size_t)(ct * 128) * KD;

    // staging descriptors: round i covers 16B-slots [i*256 .. i*256+256)
    const unsigned short* agp[4];
    int boff[4];
    int wslot[4];
    for (int i = 0; i < 4; i++) {
        int s = i * 256 + wave * 64 + lane;
        int r = s >> 3;
        int c = (s & 7) ^ (r & 7);
        int p = row0 + r;
        bool sv = (p < rend);
        const unsigned short* arow;
        if (GATHER) arow = sv ? A + (size_t)tok[p] * LDA : A;
        else        arow = sv ? A + (size_t)p * LDA      : A;
        agp[i]  = arow + c * 8;
        boff[i] = r * KD + c * 8;
        wslot[i] = (i * 256 + wave * 64) * 8;    // wave-uniform LDS base (shorts)
    }

    int arow_[4], brow_[4];
    for (int mt = 0; mt < 4; mt++) arow_[mt] = wm * 64 + mt * 16 + l15;
    for (int nt = 0; nt < 4; nt++) brow_[nt] = wn * 64 + nt * 16 + l15;

    f32x4 acc[4][4];
    for (int mt = 0; mt < 4; mt++)
        for (int nt = 0; nt < 4; nt++) acc[mt][nt] = (f32x4){0.f, 0.f, 0.f, 0.f};

#define STAGE(buf, kk)                                          \
    for (int i = 0; i < 4; i++) {                               \
        glds16(agp[i] + (kk),            &As[buf][wslot[i]]);   \
        glds16(bptr + boff[i] + (kk),    &Bs[buf][wslot[i]]);   \
    }

    // prologue: tile 0 into buf 0
    STAGE(0, 0);
    __builtin_amdgcn_sched_barrier(0);
    asm volatile("s_waitcnt vmcnt(0)" ::: "memory");
    __builtin_amdgcn_s_barrier();
    __builtin_amdgcn_sched_barrier(0);

    int cur = 0;
    for (int k0 = 0; k0 < KD; k0 += 64) {
        if (k0 + 64 < KD) { STAGE(cur ^ 1, k0 + 64); }   // prefetch next tile
        // compute current tile
        for (int ks = 0; ks < 2; ks++) {
            int kc = ks * 4 + qq;
            bf16x8 af[4], bq[4];
            for (int mt = 0; mt < 4; mt++)
                af[mt] = *(bf16x8*)&As[cur][(arow_[mt] * 8 + (kc ^ (arow_[mt] & 7))) * 8];
            for (int nt = 0; nt < 4; nt++)
                bq[nt] = *(bf16x8*)&Bs[cur][(brow_[nt] * 8 + (kc ^ (brow_[nt] & 7))) * 8];
            for (int mt = 0; mt < 4; mt++)
                for (int nt = 0; nt < 4; nt++)
                    acc[mt][nt] = __builtin_amdgcn_mfma_f32_16x16x32_bf16(
                        af[mt], bq[nt], acc[mt][nt], 0, 0, 0);
        }
        __builtin_amdgcn_sched_barrier(0);
        asm volatile("s_waitcnt vmcnt(0)" ::: "memory");  // prefetch landed
        __builtin_amdgcn_s_barrier();                     // all waves past compute
        __builtin_amdgcn_sched_barrier(0);
        cur ^= 1;
    }
#undef STAGE

    for (int mt = 0; mt < 4; mt++) {
        int rb = wm * 64 + mt * 16 + qq * 4;
        for (int reg = 0; reg < 4; reg++) {
            int p = row0 + rb + reg;
            if (p >= rend) continue;
            for (int nt = 0; nt < 4; nt++) {
                int col = ct * 128 + wn * 64 + nt * 16 + l15;
                C[(size_t)p * ND + col] = f2b(acc[mt][nt][reg]);
            }
        }
    }
}

// ---------------- SwiGLU: inter = silu(h[:, :I]) * h[:, I:2I], in place ----------------

__global__ void swiglu_k(unsigned short* __restrict__ h) {   // [NK][2I]
    int gid = blockIdx.x * 256 + threadIdx.x;                // NK * I/8 threads
    int row = gid >> 8;                                      // wait: ID/8 = 176, not 256
    // ID/8 = 176 chunks per row
    row = gid / (ID / 8);
    int c8 = (gid - row * (ID / 8)) * 8;
    unsigned short* hr = h + (size_t)row * (2 * ID);
    uint4 gv = *(const uint4*)(hr + c8);
    uint4 uv = *(const uint4*)(hr + ID + c8);
    const unsigned short* ga = (const unsigned short*)&gv;
    const unsigned short* ua = (const unsigned short*)&uv;
    uint4 o;
    unsigned int* ro = (unsigned int*)&o;
    for (int i = 0; i < 4; i++) {
        float g0 = b2f(ga[2 * i]),     u0 = b2f(ua[2 * i]);
        float g1 = b2f(ga[2 * i + 1]), u1 = b2f(ua[2 * i + 1]);
        float s0 = (g0 / (1.f + __expf(-g0))) * u0;
        float s1 = (g1 / (1.f + __expf(-g1))) * u1;
        ro[i] = f2b(s0) | ((unsigned int)f2b(s1) << 16);
    }
    *(uint4*)(hr + c8) = o;   // gate half becomes inter (same thread read both halves)
}

// ---------------- weighted gather combine ----------------

__global__ void combine_k(const unsigned short* __restrict__ outs,  // [NK][H] bf16
                          const int* __restrict__ inv,              // [NK]
                          const void* __restrict__ w,               // [N][K]
                          void* __restrict__ out,                   // [N][H]
                          const int* __restrict__ mode) {
    bool fp32m = (mode[0] != 0);
    int gid = blockIdx.x * 256 + threadIdx.x;   // N*H/8 threads
    int t  = gid >> 8;                          // H/8 = 256 chunks per token
    int c8 = (gid & 255) * 8;
    int p0 = inv[t * 2], p1 = inv[t * 2 + 1];
    float w0, w1;
    if (fp32m) {
        const float* wf = (const float*)w;
        w0 = wf[t * 2]; w1 = wf[t * 2 + 1];
    } else {
        const unsigned short* wu = (const unsigned short*)w;
        w0 = b2f(wu[t * 2]); w1 = b2f(wu[t * 2 + 1]);
    }
    uint4 v0 = *(const uint4*)(outs + (size_t)p0 * HD + c8);
    uint4 v1 = *(const uint4*)(outs + (size_t)p1 * HD + c8);
    const unsigned short* a = (const unsigned short*)&v0;
    const unsigned short* b = (const unsigned short*)&v1;
    float r[8];
    for (int i = 0; i < 8; i++) r[i] = w0 * b2f(a[i]) + w1 * b2f(b[i]);
    if (fp32m) {
        float* of = (float*)out + (size_t)t * HD + c8;
        *(float4*)of       = make_float4(r[0], r[1], r[2], r[3]);
        *(float4*)(of + 4) = make_float4(r[4], r[5], r[6], r[7]);
    } else {
        uint4 o;
        unsigned int* ro = (unsigned int*)&o;
        for (int i = 0; i < 4; i++)
            ro[i] = f2b(r[2 * i]) | ((unsigned int)f2b(r[2 * i + 1]) << 16);
        *(uint4*)((unsigned short*)out + (size_t)t * HD + c8) = o;
    }
}

// ---------------- launch ----------------

extern "C" void kernel_launch(void* const* d_in, const int* in_sizes, int n_in,
                              void* d_out, int out_size, void* d_ws, size_t ws_size,
                              hipStream_t stream) {
    const void* x   = d_in[0];                 // [N][H] fp32 or bf16
    const int*  idx = (const int*)d_in[1];     // [N][K] i32
    const void* w   = d_in[2];                 // [N][K] fp32 or bf16
    const void* gup = d_in[3];                 // [E][H][2I]
    const void* dwn = d_in[4];                 // [E][I][H]

    char* ws = (char*)d_ws;
    int* mode = (int*)(ws);
    int* cnt  = (int*)(ws + 64);
    int* base = (int*)(ws + 128);              // 9 ints
    int* fill = (int*)(ws + 192);
    int* tb   = (int*)(ws + 256);              // 9 ints (tile prefix)
    int* tok  = (int*)(ws + 512);
    int* inv  = (int*)(ws + 512 + 4 * NK);
    // big arrays (shorts); outs aliases gupT (dead after gemm1). total ~264.5 MB.
    unsigned short* h    = (unsigned short*)(ws + 262144);           // [NK][2I]
    unsigned short* xb   = h    + (size_t)NK * 2 * ID;               // [N][H]
    unsigned short* dwnT = xb   + (size_t)N_TOK * HD;                // [E][H][I]
    unsigned short* gupT = dwnT + (size_t)NEXP * HD * ID;            // [E][2I][H]
    unsigned short* outs = gupT;                                     // [NK][H] alias

    probe_k<<<1, 1024, 0, stream>>>((const unsigned short*)x, mode);
    convert_x<<<(N_TOK * HD / 8) / 256, 256, 0, stream>>>(x, xb, mode);

    init_k<<<1, 64, 0, stream>>>(cnt, fill);
    route_count<<<NK / 256, 256, 0, stream>>>(idx, cnt);
    route_scan<<<1, 64, 0, stream>>>(cnt, base, tb);
    route_scatter<<<NK / 256, 256, 0, stream>>>(idx, base, fill, tok, inv);

    transpose_k<<<dim3(2 * ID / 64, HD / 64, NEXP), 256, 0, stream>>>(
        gup, gupT, HD, 2 * ID, mode);
    transpose_k<<<dim3(HD / 64, ID / 64, NEXP), 256, 0, stream>>>(
        dwn, dwnT, ID, HD, mode);

    // gemm1: h[NK][2816] = xb @ gupT  (gather rows via tok)
    gemm_k<HD, 2 * ID, HD, true><<<MAXRT * (2 * ID / 128), 256, 0, stream>>>(
        xb, gupT, base, tb, tok, h);
    // swiglu in place: h[:, :ID] = silu(h[:, :ID]) * h[:, ID:]
    swiglu_k<<<(NK * (ID / 8)) / 256, 256, 0, stream>>>(h);
    // gemm2: outs[NK][2048] = h[:, :ID] @ dwnT   (LDA = 2816)
    gemm_k<ID, HD, 2 * ID, false><<<MAXRT * (HD / 128), 256, 0, stream>>>(
        h, dwnT, base, tb, tok, outs);

    combine_k<<<(N_TOK * HD / 8) / 256, 256, 0, stream>>>(outs, inv, w, d_out, mode);
}

// Round 2
// 941.254 us; speedup vs baseline: 1.1524x; 1.0510x over previous
//
#include <hip/hip_runtime.h>

// MoE experts: N=8192, K=2, E=8, H=2048, I=1408.
// Round 5: 256x256 8-phase counted-vmcnt GEMM (T3+T4+T5 on top of T1+T2).
// 512 threads / 8 waves, BK=64, 128 KiB dbuf LDS, vmcnt(6) at phases 4/8 only,
// setprio around MFMA clusters. Derived phase/stage schedule (race-checked):
//   p1: readB(b0)+readA(b0,m01), stage b1.Ah1(t+1)
//   p2: readA(b0,m23),           stage b0.Bh0(t+2)
//   p3: readA(b0,m45),           stage b0.Bh1(t+2)
//   p4: readA(b0,m67),           stage b0.Ah0(t+2), vmcnt(6)
//   p5: readB(b1)+readA(b1,m01), stage b0.Ah1(t+2)
//   p6: readA(b1,m23),           stage b1.Bh0(t+3)
//   p7: readA(b1,m45),           stage b1.Bh1(t+3)
//   p8: readA(b1,m67),           stage b1.Ah0(t+3), vmcnt(6)

#define N_TOK 8192
#define TOPK  2
#define NEXP  8
#define HD    2048
#define ID    1408
#define NK    (N_TOK * TOPK)     // 16384
#define NT256 (NK / 256 + NEXP)  // 72 max 256-row tiles over all experts

typedef __bf16 bf16x8 __attribute__((ext_vector_type(8)));
typedef float  f32x4  __attribute__((ext_vector_type(4)));

__device__ __forceinline__ float b2f(unsigned short u) {
    union { unsigned int i; float f; } v; v.i = ((unsigned int)u) << 16; return v.f;
}
__device__ __forceinline__ unsigned short f2b(float f) {
    union { float f; unsigned int i; } v; v.f = f;
    unsigned int x = v.i;
    return (unsigned short)((x + 0x7fffu + ((x >> 16) & 1u)) >> 16);   // RNE
}

// async global->LDS, 16B per lane; dest = wave-uniform base + lane*16
__device__ __forceinline__ void glds16(const void* g, void* l) {
    __builtin_amdgcn_global_load_lds(
        (const __attribute__((address_space(1))) unsigned int*)g,
        (__attribute__((address_space(3))) unsigned int*)l,
        16, 0, 0);
}

// ---------------- dtype probe: 1 = fp32 storage, 0 = bf16 storage ----------------

__global__ void probe_k(const unsigned short* __restrict__ xu, int* __restrict__ mode) {
    __shared__ int c;
    if (threadIdx.x == 0) c = 0;
    __syncthreads();
    float a = fabsf(b2f(xu[threadIdx.x * 2]));
    int sane = (a > 1e-4f && a < 100.f) ? 1 : 0;
    atomicAdd(&c, sane);
    __syncthreads();
    if (threadIdx.x == 0) mode[0] = (c < 512) ? 1 : 0;
}

// ---------------- x -> bf16 ----------------

__global__ void convert_x(const void* __restrict__ x, unsigned short* __restrict__ xb,
                          const int* __restrict__ mode) {
    int gid = blockIdx.x * 256 + threadIdx.x;      // N*H/8 threads
    size_t o = (size_t)gid * 8;
    if (mode[0]) {
        const float* f = (const float*)x + o;
        float4 f0 = *(const float4*)f;
        float4 f1 = *(const float4*)(f + 4);
        uint4 v;
        v.x = f2b(f0.x) | ((unsigned int)f2b(f0.y) << 16);
        v.y = f2b(f0.z) | ((unsigned int)f2b(f0.w) << 16);
        v.z = f2b(f1.x) | ((unsigned int)f2b(f1.y) << 16);
        v.w = f2b(f1.z) | ((unsigned int)f2b(f1.w) << 16);
        *(uint4*)(xb + o) = v;
    } else {
        *(uint4*)(xb + o) = *(const uint4*)((const unsigned short*)x + o);
    }
}

// ---------------- routing ----------------

__global__ void init_k(int* cnt, int* fill) {
    int t = threadIdx.x;
    if (t < NEXP) { cnt[t] = 0; fill[t] = 0; }
}

__global__ void route_count(const int* __restrict__ idx, int* __restrict__ cnt) {
    int s = blockIdx.x * 256 + threadIdx.x;
    if (s < NK) atomicAdd(&cnt[idx[s]], 1);
}

__global__ void route_scan(const int* __restrict__ cnt, int* __restrict__ base,
                           int* __restrict__ tb) {
    if (threadIdx.x == 0) {
        int acc = 0, tacc = 0;
        for (int e = 0; e < NEXP; e++) {
            base[e] = acc; tb[e] = tacc;
            acc += cnt[e]; tacc += (cnt[e] + 255) >> 8;
        }
        base[NEXP] = acc; tb[NEXP] = tacc;
    }
}

__global__ void route_scatter(const int* __restrict__ idx,
                              const int* __restrict__ base,
                              int* __restrict__ fill,
                              int* __restrict__ tok,
                              int* __restrict__ inv) {
    int s = blockIdx.x * 256 + threadIdx.x;
    if (s < NK) {
        int e = idx[s];
        int p = base[e] + atomicAdd(&fill[e], 1);
        tok[p] = s >> 1;           // TOPK == 2
        inv[s] = p;
    }
}

// ---------------- weight transpose: per-expert [R][C] (fp32 or bf16) -> [C][R] bf16 ----

__global__ void transpose_k(const void* __restrict__ in, unsigned short* __restrict__ out,
                            int R, int C, const int* __restrict__ mode) {
    __shared__ float tile[64][65];
    bool fp32m = (mode[0] != 0);
    int e  = blockIdx.z;
    int c0 = blockIdx.x * 64, r0 = blockIdx.y * 64;
    int t = threadIdx.x;
    if (fp32m) {
        const float* inp = (const float*)in + (size_t)e * R * C;
        for (int i = 0; i < 16; i++) {
            int lin = t + i * 256;
            int r = lin >> 6, c = lin & 63;
            tile[r][c] = inp[(size_t)(r0 + r) * C + c0 + c];
        }
    } else {
        const unsigned int* inp = (const unsigned int*)in + (size_t)e * R * (C >> 1);
        for (int i = 0; i < 8; i++) {
            int lin = t + i * 256;
            int r = lin >> 5, cu = lin & 31;
            unsigned int v = inp[(size_t)(r0 + r) * (C >> 1) + (c0 >> 1) + cu];
            tile[r][2 * cu]     = b2f((unsigned short)(v & 0xffffu));
            tile[r][2 * cu + 1] = b2f((unsigned short)(v >> 16));
        }
    }
    __syncthreads();
    unsigned int* outp = (unsigned int*)out + (size_t)e * C * (R >> 1);
    for (int i = 0; i < 8; i++) {
        int lin = t + i * 256;
        int c = lin >> 5, ru = lin & 31;
        unsigned int lo = f2b(tile[2 * ru][c]);
        unsigned int hi = f2b(tile[2 * ru + 1][c]);
        outp[(size_t)(c0 + c) * (R >> 1) + (r0 >> 1) + ru] = lo | (hi << 16);
    }
}

// LDS swizzle (proven, 0 bank conflicts): element (row r, k-chunk c8) lives at
// 16B-slot r*8 + (c8 ^ (r&7)). DMA writes slots linearly with the inverse
// permutation on the global source address.

// ---------------- grouped GEMM, 256x256 tile, BK=64, 8-phase counted-vmcnt ----
// A: [rows][LDA] bf16 (row via tok[] if GATHER), B: [E][ND][KD] bf16 (transposed),
// C: [NK][ND] bf16.  512 threads. Grid: NT256 * (ND/256) blocks, exact via tb[].

template<int KD, int ND, int LDA, bool GATHER>
__launch_bounds__(512, 2)
__global__ void gemm8_k(const unsigned short* __restrict__ A,
                        const unsigned short* __restrict__ B,
                        const int* __restrict__ base,
                        const int* __restrict__ tb,
                        const int* __restrict__ tok,
                        unsigned short* __restrict__ C) {
    extern __shared__ unsigned short lds[];   // 128 KiB: A[2][256][64] | B[2][256][64]
    const int CT = ND / 256;
    const int KT = KD / 64;
    int G = gridDim.x;
    int orig = blockIdx.x;
    int q8 = G >> 3, r8 = G & 7, xcd = orig & 7, lin = orig >> 3;
    int wgid = (xcd < r8 ? xcd * (q8 + 1) : r8 * (q8 + 1) + (xcd - r8) * q8) + lin;
    int ct  = wgid % CT;          // ct-minor: consecutive ids share the A panel
    int rtf = wgid / CT;
    if (rtf >= tb[NEXP]) return;
    int e = 0;
    while (tb[e + 1] <= rtf) e++;
    int row0 = base[e] + (rtf - tb[e]) * 256;
    int rend = base[e + 1];

    int tid  = threadIdx.x;
    int lane = tid & 63;
    int wave = tid >> 6;
    int wm16 = (wave & 1) * 16;
    int wn16 = (wave >> 1) * 16;
    int l15 = lane & 15, qq = lane >> 4;
    int l7  = l15 & 7;

    const unsigned short* bbase = B + (size_t)e * ND * KD + (size_t)(ct * 256) * KD;

    // staging source pointers: round j in {0,1}, half h in {0,1}
    // slot s = j*512 + tid -> r = s>>3 (0..127), c = (s&7)^(r&7)
    const unsigned short* agp[2][2];
    const unsigned short* bgp[2][2];
    for (int j = 0; j < 2; j++) {
        int s = j * 512 + tid;
        int r = s >> 3;
        int c = (s & 7) ^ (r & 7);
        for (int h = 0; h < 2; h++) {
            int p = row0 + h * 128 + r;
            bool sv = (p < rend);
            const unsigned short* ar;
            if (GATHER) ar = sv ? A + (size_t)tok[p] * LDA : A;
            else        ar = sv ? A + (size_t)p * LDA      : A;
            agp[j][h] = ar + c * 8;
            bgp[j][h] = bbase + (size_t)(h * 128 + r) * KD + c * 8;
        }
    }
    int wbase = wave * 512;   // wave-uniform LDS short-offset within a round

    f32x4 acc[8][4];
#pragma unroll
    for (int m = 0; m < 8; m++)
#pragma unroll
        for (int n = 0; n < 4; n++) acc[m][n] = (f32x4){0.f, 0.f, 0.f, 0.f};

    bf16x8 af0[2], af1[2], bq[4][2];

// LDS layout (shorts): A: buf*16384 + h*8192 + j*4096 + slotpart; B: +32768
#define STAGE_A(buf, h, kt) do { int _k = ((kt) < KT ? (kt) : KT - 1) * 64;     \
    glds16(agp[0][h] + _k, &lds[(buf) * 16384 + (h) * 8192 + wbase]);           \
    glds16(agp[1][h] + _k, &lds[(buf) * 16384 + (h) * 8192 + 4096 + wbase]); } while (0)
#define STAGE_B(buf, h, kt) do { int _k = ((kt) < KT ? (kt) : KT - 1) * 64;     \
    glds16(bgp[0][h] + _k, &lds[32768 + (buf) * 16384 + (h) * 8192 + wbase]);   \
    glds16(bgp[1][h] + _k, &lds[32768 + (buf) * 16384 + (h) * 8192 + 4096 + wbase]); } while (0)

#define ALDS(buf, m, ks) (*(const bf16x8*)&lds[(buf) * 16384 +                  \
    (((m) * 32 + wm16 + l15) * 8 + ((((ks) * 4) + qq) ^ l7)) * 8])
#define BLDS(buf, n, ks) (*(const bf16x8*)&lds[32768 + (buf) * 16384 +          \
    (((n) * 64 + wn16 + l15) * 8 + ((((ks) * 4) + qq) ^ l7)) * 8])

#define PH_READA(buf, m0)                                                       \
    af0[0] = ALDS(buf, m0, 0); af0[1] = ALDS(buf, m0, 1);                       \
    af1[0] = ALDS(buf, (m0) + 1, 0); af1[1] = ALDS(buf, (m0) + 1, 1);
#define PH_READB(buf)                                                           \
    _Pragma("unroll") for (int n = 0; n < 4; n++) {                             \
        bq[n][0] = BLDS(buf, n, 0); bq[n][1] = BLDS(buf, n, 1); }

#define MFMA16(m0) do {                                                         \
    _Pragma("unroll") for (int n = 0; n < 4; n++) {                             \
        acc[m0][n] = __builtin_amdgcn_mfma_f32_16x16x32_bf16(af0[0], bq[n][0], acc[m0][n], 0, 0, 0);         \
        acc[m0][n] = __builtin_amdgcn_mfma_f32_16x16x32_bf16(af0[1], bq[n][1], acc[m0][n], 0, 0, 0);         \
        acc[(m0) + 1][n] = __builtin_amdgcn_mfma_f32_16x16x32_bf16(af1[0], bq[n][0], acc[(m0) + 1][n], 0, 0, 0); \
        acc[(m0) + 1][n] = __builtin_amdgcn_mfma_f32_16x16x32_bf16(af1[1], bq[n][1], acc[(m0) + 1][n], 0, 0, 0); } } while (0)

#define SYNCA(m0)                                                               \
    __builtin_amdgcn_sched_barrier(0);                                          \
    __builtin_amdgcn_s_barrier();                                               \
    asm volatile("s_waitcnt lgkmcnt(0)" ::: "memory");                          \
    __builtin_amdgcn_sched_barrier(0);                                          \
    __builtin_amdgcn_s_setprio(1);                                              \
    MFMA16(m0);                                                                 \
    __builtin_amdgcn_s_setprio(0);                                              \
    __builtin_amdgcn_sched_barrier(0);                                          \
    __builtin_amdgcn_s_barrier();

#define SYNCV(m0)                                                               \
    __builtin_amdgcn_sched_barrier(0);                                          \
    asm volatile("s_waitcnt vmcnt(6)" ::: "memory");                            \
    __builtin_amdgcn_s_barrier();                                               \
    asm volatile("s_waitcnt lgkmcnt(0)" ::: "memory");                          \
    __builtin_amdgcn_sched_barrier(0);                                          \
    __builtin_amdgcn_s_setprio(1);                                              \
    MFMA16(m0);                                                                 \
    __builtin_amdgcn_s_setprio(0);                                              \
    __builtin_amdgcn_sched_barrier(0);                                          \
    __builtin_amdgcn_s_barrier();

    // prologue: tile0 (4 halves) + tile1's Bh0,Bh1,Ah0; drain tile0, keep 3 in flight
    STAGE_A(0, 0, 0); STAGE_A(0, 1, 0); STAGE_B(0, 0, 0); STAGE_B(0, 1, 0);
    STAGE_B(1, 0, 1); STAGE_B(1, 1, 1); STAGE_A(1, 0, 1);
    __builtin_amdgcn_sched_barrier(0);
    asm volatile("s_waitcnt vmcnt(6)" ::: "memory");
    __builtin_amdgcn_s_barrier();
    __builtin_amdgcn_sched_barrier(0);

    for (int i = 0; i < KT / 2; i++) {
        int t1 = 2 * i + 1, t2 = 2 * i + 2, t3 = 2 * i + 3;
        PH_READB(0); PH_READA(0, 0); STAGE_A(1, 1, t1); SYNCA(0);   // p1
        PH_READA(0, 2);              STAGE_B(0, 0, t2); SYNCA(2);   // p2
        PH_READA(0, 4);              STAGE_B(0, 1, t2); SYNCA(4);   // p3
        PH_READA(0, 6);              STAGE_A(0, 0, t2); SYNCV(6);   // p4
        PH_READB(1); PH_READA(1, 0); STAGE_A(0, 1, t2); SYNCA(0);   // p5
        PH_READA(1, 2);              STAGE_B(1, 0, t3); SYNCA(2);   // p6
        PH_READA(1, 4);              STAGE_B(1, 1, t3); SYNCA(4);   // p7
        PH_READA(1, 6);              STAGE_A(1, 0, t3); SYNCV(6);   // p8
    }
    asm volatile("s_waitcnt vmcnt(0)" ::: "memory");   // retire leftover DMA

#undef STAGE_A
#undef STAGE_B
#undef ALDS
#undef BLDS
#undef PH_READA
#undef PH_READB
#undef MFMA16
#undef SYNCA
#undef SYNCV

#pragma unroll
    for (int m = 0; m < 8; m++) {
        int rbase = row0 + m * 32 + wm16 + qq * 4;
#pragma unroll
        for (int reg = 0; reg < 4; reg++) {
            int p = rbase + reg;
            if (p >= rend) continue;
#pragma unroll
            for (int n = 0; n < 4; n++) {
                int col = ct * 256 + n * 64 + wn16 + l15;
                C[(size_t)p * ND + col] = f2b(acc[m][n][reg]);
            }
        }
    }
}

// ---------------- SwiGLU: h[:, :I] = silu(h[:, :I]) * h[:, I:2I], in place ----------

__global__ void swiglu_k(unsigned short* __restrict__ h) {   // [NK][2I]
    int gid = blockIdx.x * 256 + threadIdx.x;                // NK * (I/8) threads
    int row = gid / (ID / 8);
    int c8 = (gid - row * (ID / 8)) * 8;
    unsigned short* hr = h + (size_t)row * (2 * ID);
    uint4 gv = *(const uint4*)(hr + c8);
    uint4 uv = *(const uint4*)(hr + ID + c8);
    const unsigned short* ga = (const unsigned short*)&gv;
    const unsigned short* ua = (const unsigned short*)&uv;
    uint4 o;
    unsigned int* ro = (unsigned int*)&o;
    for (int i = 0; i < 4; i++) {
        float g0 = b2f(ga[2 * i]),     u0 = b2f(ua[2 * i]);
        float g1 = b2f(ga[2 * i + 1]), u1 = b2f(ua[2 * i + 1]);
        float s0 = (g0 / (1.f + __expf(-g0))) * u0;
        float s1 = (g1 / (1.f + __expf(-g1))) * u1;
        ro[i] = f2b(s0) | ((unsigned int)f2b(s1) << 16);
    }
    *(uint4*)(hr + c8) = o;
}

// ---------------- weighted gather combine ----------------

__global__ void combine_k(const unsigned short* __restrict__ outs,  // [NK][H] bf16
                          const int* __restrict__ inv,              // [NK]
                          const void* __restrict__ w,               // [N][K]
                          void* __restrict__ out,                   // [N][H]
                          const int* __restrict__ mode) {
    bool fp32m = (mode[0] != 0);
    int gid = blockIdx.x * 256 + threadIdx.x;   // N*H/8 threads
    int t  = gid >> 8;                          // H/8 = 256 chunks per token
    int c8 = (gid & 255) * 8;
    int p0 = inv[t * 2], p1 = inv[t * 2 + 1];
    float w0, w1;
    if (fp32m) {
        const float* wf = (const float*)w;
        w0 = wf[t * 2]; w1 = wf[t * 2 + 1];
    } else {
        const unsigned short* wu = (const unsigned short*)w;
        w0 = b2f(wu[t * 2]); w1 = b2f(wu[t * 2 + 1]);
    }
    uint4 v0 = *(const uint4*)(outs + (size_t)p0 * HD + c8);
    uint4 v1 = *(const uint4*)(outs + (size_t)p1 * HD + c8);
    const unsigned short* a = (const unsigned short*)&v0;
    const unsigned short* b = (const unsigned short*)&v1;
    float r[8];
    for (int i = 0; i < 8; i++) r[i] = w0 * b2f(a[i]) + w1 * b2f(b[i]);
    if (fp32m) {
        float* of = (float*)out + (size_t)t * HD + c8;
        *(float4*)of       = make_float4(r[0], r[1], r[2], r[3]);
        *(float4*)(of + 4) = make_float4(r[4], r[5], r[6], r[7]);
    } else {
        uint4 o;
        unsigned int* ro = (unsigned int*)&o;
        for (int i = 0; i < 4; i++)
            ro[i] = f2b(r[2 * i]) | ((unsigned int)f2b(r[2 * i + 1]) << 16);
        *(uint4*)((unsigned short*)out + (size_t)t * HD + c8) = o;
    }
}

// ---------------- launch ----------------

extern "C" void kernel_launch(void* const* d_in, const int* in_sizes, int n_in,
                              void* d_out, int out_size, void* d_ws, size_t ws_size,
                              hipStream_t stream) {
    const void* x   = d_in[0];                 // [N][H] fp32 or bf16
    const int*  idx = (const int*)d_in[1];     // [N][K] i32
    const void* w   = d_in[2];                 // [N][K] fp32 or bf16
    const void* gup = d_in[3];                 // [E][H][2I]
    const void* dwn = d_in[4];                 // [E][I][H]

    char* ws = (char*)d_ws;
    int* mode = (int*)(ws);
    int* cnt  = (int*)(ws + 64);
    int* base = (int*)(ws + 128);              // 9 ints
    int* fill = (int*)(ws + 192);
    int* tb   = (int*)(ws + 256);              // 9 ints (256-row tile prefix)
    int* tok  = (int*)(ws + 512);
    int* inv  = (int*)(ws + 512 + 4 * NK);
    // big arrays (shorts); outs aliases gupT (dead after gemm1). total ~264.5 MB.
    unsigned short* h    = (unsigned short*)(ws + 262144);           // [NK][2I]
    unsigned short* xb   = h    + (size_t)NK * 2 * ID;               // [N][H]
    unsigned short* dwnT = xb   + (size_t)N_TOK * HD;                // [E][H][I]
    unsigned short* gupT = dwnT + (size_t)NEXP * HD * ID;            // [E][2I][H]
    unsigned short* outs = gupT;                                     // [NK][H] alias

    static bool attr_done = false;
    if (!attr_done) {
        hipFuncSetAttribute(
            reinterpret_cast<const void*>(&gemm8_k<HD, 2 * ID, HD, true>),
            hipFuncAttributeMaxDynamicSharedMemorySize, 131072);
        hipFuncSetAttribute(
            reinterpret_cast<const void*>(&gemm8_k<ID, HD, 2 * ID, false>),
            hipFuncAttributeMaxDynamicSharedMemorySize, 131072);
        attr_done = true;
    }

    probe_k<<<1, 1024, 0, stream>>>((const unsigned short*)x, mode);
    convert_x<<<(N_TOK * HD / 8) / 256, 256, 0, stream>>>(x, xb, mode);

    init_k<<<1, 64, 0, stream>>>(cnt, fill);
    route_count<<<NK / 256, 256, 0, stream>>>(idx, cnt);
    route_scan<<<1, 64, 0, stream>>>(cnt, base, tb);
    route_scatter<<<NK / 256, 256, 0, stream>>>(idx, base, fill, tok, inv);

    transpose_k<<<dim3(2 * ID / 64, HD / 64, NEXP), 256, 0, stream>>>(
        gup, gupT, HD, 2 * ID, mode);
    transpose_k<<<dim3(HD / 64, ID / 64, NEXP), 256, 0, stream>>>(
        dwn, dwnT, ID, HD, mode);

    // gemm1: h[NK][2816] = xb @ gupT  (gather rows via tok)
    gemm8_k<HD, 2 * ID, HD, true>
        <<<NT256 * (2 * ID / 256), 512, 131072, stream>>>(xb, gupT, base, tb, tok, h);
    // swiglu in place: h[:, :ID] = silu(h[:, :ID]) * h[:, ID:]
    swiglu_k<<<(NK * (ID / 8)) / 256, 256, 0, stream>>>(h);
    // gemm2: outs[NK][2048] = h[:, :ID] @ dwnT   (LDA = 2816)
    gemm8_k<ID, HD, 2 * ID, false>
        <<<NT256 * (HD / 256), 512, 131072, stream>>>(h, dwnT, base, tb, tok, outs);

    combine_k<<<(N_TOK * HD / 8) / 256, 256, 0, stream>>>(outs, inv, w, d_out, mode);
}

// Round 3
// 905.051 us; speedup vs baseline: 1.1985x; 1.0400x over previous
//
#include <hip/hip_runtime.h>

// MoE experts: N=8192, K=2, E=8, H=2048, I=1408.
// Round 6: fuse SwiGLU into gemm1 via 64-col-interleaved gupT (gate64|up64 row
// blocks) -> epilogue computes silu(g)*u in-thread, writes inter[NK][I] directly.
// swiglu_k deleted; gemm2 reads dense inter (LDA=ID). GEMM core unchanged:
// 256x256 8-phase counted-vmcnt (T3+T4+T5 on T1+T2), 512 thr, 128 KiB dbuf LDS.

#define N_TOK 8192
#define TOPK  2
#define NEXP  8
#define HD    2048
#define ID    1408
#define NK    (N_TOK * TOPK)     // 16384
#define NT256 (NK / 256 + NEXP)  // 72 max 256-row tiles over all experts

typedef __bf16 bf16x8 __attribute__((ext_vector_type(8)));
typedef float  f32x4  __attribute__((ext_vector_type(4)));

__device__ __forceinline__ float b2f(unsigned short u) {
    union { unsigned int i; float f; } v; v.i = ((unsigned int)u) << 16; return v.f;
}
__device__ __forceinline__ unsigned short f2b(float f) {
    union { float f; unsigned int i; } v; v.f = f;
    unsigned int x = v.i;
    return (unsigned short)((x + 0x7fffu + ((x >> 16) & 1u)) >> 16);   // RNE
}

// async global->LDS, 16B per lane; dest = wave-uniform base + lane*16
__device__ __forceinline__ void glds16(const void* g, void* l) {
    __builtin_amdgcn_global_load_lds(
        (const __attribute__((address_space(1))) unsigned int*)g,
        (__attribute__((address_space(3))) unsigned int*)l,
        16, 0, 0);
}

// ---------------- dtype probe: 1 = fp32 storage, 0 = bf16 storage ----------------

__global__ void probe_k(const unsigned short* __restrict__ xu, int* __restrict__ mode) {
    __shared__ int c;
    if (threadIdx.x == 0) c = 0;
    __syncthreads();
    float a = fabsf(b2f(xu[threadIdx.x * 2]));
    int sane = (a > 1e-4f && a < 100.f) ? 1 : 0;
    atomicAdd(&c, sane);
    __syncthreads();
    if (threadIdx.x == 0) mode[0] = (c < 512) ? 1 : 0;
}

// ---------------- x -> bf16 ----------------

__global__ void convert_x(const void* __restrict__ x, unsigned short* __restrict__ xb,
                          const int* __restrict__ mode) {
    int gid = blockIdx.x * 256 + threadIdx.x;      // N*H/8 threads
    size_t o = (size_t)gid * 8;
    if (mode[0]) {
        const float* f = (const float*)x + o;
        float4 f0 = *(const float4*)f;
        float4 f1 = *(const float4*)(f + 4);
        uint4 v;
        v.x = f2b(f0.x) | ((unsigned int)f2b(f0.y) << 16);
        v.y = f2b(f0.z) | ((unsigned int)f2b(f0.w) << 16);
        v.z = f2b(f1.x) | ((unsigned int)f2b(f1.y) << 16);
        v.w = f2b(f1.z) | ((unsigned int)f2b(f1.w) << 16);
        *(uint4*)(xb + o) = v;
    } else {
        *(uint4*)(xb + o) = *(const uint4*)((const unsigned short*)x + o);
    }
}

// ---------------- routing ----------------

__global__ void init_k(int* cnt, int* fill) {
    int t = threadIdx.x;
    if (t < NEXP) { cnt[t] = 0; fill[t] = 0; }
}

__global__ void route_count(const int* __restrict__ idx, int* __restrict__ cnt) {
    int s = blockIdx.x * 256 + threadIdx.x;
    if (s < NK) atomicAdd(&cnt[idx[s]], 1);
}

__global__ void route_scan(const int* __restrict__ cnt, int* __restrict__ base,
                           int* __restrict__ tb) {
    if (threadIdx.x == 0) {
        int acc = 0, tacc = 0;
        for (int e = 0; e < NEXP; e++) {
            base[e] = acc; tb[e] = tacc;
            acc += cnt[e]; tacc += (cnt[e] + 255) >> 8;
        }
        base[NEXP] = acc; tb[NEXP] = tacc;
    }
}

__global__ void route_scatter(const int* __restrict__ idx,
                              const int* __restrict__ base,
                              int* __restrict__ fill,
                              int* __restrict__ tok,
                              int* __restrict__ inv) {
    int s = blockIdx.x * 256 + threadIdx.x;
    if (s < NK) {
        int e = idx[s];
        int p = base[e] + atomicAdd(&fill[e], 1);
        tok[p] = s >> 1;           // TOPK == 2
        inv[s] = p;
    }
}

// ---------------- weight transpose: per-expert [R][C] -> [C'][R] bf16 ----------------
// ilv: interleave 64-col blocks of gate (cc < ID) and up (cc >= ID):
//   gate col j -> out-row (j>>6)*128 + (j&63);  up col j -> (j>>6)*128 + 64 + (j&63)

__global__ void transpose_k(const void* __restrict__ in, unsigned short* __restrict__ out,
                            int R, int C, int ilv, const int* __restrict__ mode) {
    __shared__ float tile[64][65];
    bool fp32m = (mode[0] != 0);
    int e  = blockIdx.z;
    int c0 = blockIdx.x * 64, r0 = blockIdx.y * 64;
    int t = threadIdx.x;
    if (fp32m) {
        const float* inp = (const float*)in + (size_t)e * R * C;
        for (int i = 0; i < 16; i++) {
            int lin = t + i * 256;
            int r = lin >> 6, c = lin & 63;
            tile[r][c] = inp[(size_t)(r0 + r) * C + c0 + c];
        }
    } else {
        const unsigned int* inp = (const unsigned int*)in + (size_t)e * R * (C >> 1);
        for (int i = 0; i < 8; i++) {
            int lin = t + i * 256;
            int r = lin >> 5, cu = lin & 31;
            unsigned int v = inp[(size_t)(r0 + r) * (C >> 1) + (c0 >> 1) + cu];
            tile[r][2 * cu]     = b2f((unsigned short)(v & 0xffffu));
            tile[r][2 * cu + 1] = b2f((unsigned short)(v >> 16));
        }
    }
    __syncthreads();
    unsigned int* outp = (unsigned int*)out + (size_t)e * C * (R >> 1);
    for (int i = 0; i < 8; i++) {
        int lin = t + i * 256;
        int c = lin >> 5, ru = lin & 31;
        int cc = c0 + c;
        int orow = cc;
        if (ilv) orow = (cc < ID) ? ((cc >> 6) * 128 + (cc & 63))
                                  : (((cc - ID) >> 6) * 128 + 64 + ((cc - ID) & 63));
        unsigned int lo = f2b(tile[2 * ru][c]);
        unsigned int hi = f2b(tile[2 * ru + 1][c]);
        outp[(size_t)orow * (R >> 1) + (r0 >> 1) + ru] = lo | (hi << 16);
    }
}

// LDS swizzle (proven, 0 bank conflicts): element (row r, k-chunk c8) lives at
// 16B-slot r*8 + (c8 ^ (r&7)). DMA writes slots linearly with the inverse
// permutation on the global source address.

// ---------------- grouped GEMM, 256x256 tile, BK=64, 8-phase counted-vmcnt ----
// A: [rows][LDA] bf16 (row via tok[] if GATHER), B: [E][NBTOT][KD] bf16,
// C: [NK][NC] bf16 where NC = FUSE ? NBTOT/2 : NBTOT.
// FUSE: B rows are (gate64|up64)-interleaved -> acc[m][2n2]/acc[m][2n2+1] are
// elementwise (gate, up) pairs in-thread; epilogue writes silu(g)*u.
// 512 threads. Grid: NT256 * (NBTOT/256) blocks, exact tiles via tb[].

template<int KD, int NBTOT, int LDA, bool GATHER, bool FUSE>
__launch_bounds__(512, 2)
__global__ void gemm8_k(const unsigned short* __restrict__ A,
                        const unsigned short* __restrict__ B,
                        const int* __restrict__ base,
                        const int* __restrict__ tb,
                        const int* __restrict__ tok,
                        unsigned short* __restrict__ C) {
    extern __shared__ unsigned short lds[];   // 128 KiB: A[2][256][64] | B[2][256][64]
    const int CT = NBTOT / 256;
    const int NC = FUSE ? NBTOT / 2 : NBTOT;
    const int KT = KD / 64;
    int G = gridDim.x;
    int orig = blockIdx.x;
    int q8 = G >> 3, r8 = G & 7, xcd = orig & 7, lin = orig >> 3;
    int wgid = (xcd < r8 ? xcd * (q8 + 1) : r8 * (q8 + 1) + (xcd - r8) * q8) + lin;
    int ct  = wgid % CT;          // ct-minor: consecutive ids share the A panel
    int rtf = wgid / CT;
    if (rtf >= tb[NEXP]) return;
    int e = 0;
    while (tb[e + 1] <= rtf) e++;
    int row0 = base[e] + (rtf - tb[e]) * 256;
    int rend = base[e + 1];

    int tid  = threadIdx.x;
    int lane = tid & 63;
    int wave = tid >> 6;
    int wm16 = (wave & 1) * 16;
    int wn16 = (wave >> 1) * 16;
    int l15 = lane & 15, qq = lane >> 4;
    int l7  = l15 & 7;

    const unsigned short* bbase = B + (size_t)e * NBTOT * KD + (size_t)(ct * 256) * KD;

    // staging source pointers: round j in {0,1}, half h in {0,1}
    // slot s = j*512 + tid -> r = s>>3 (0..127), c = (s&7)^(r&7)
    const unsigned short* agp[2][2];
    const unsigned short* bgp[2][2];
    for (int j = 0; j < 2; j++) {
        int s = j * 512 + tid;
        int r = s >> 3;
        int c = (s & 7) ^ (r & 7);
        for (int h = 0; h < 2; h++) {
            int p = row0 + h * 128 + r;
            bool sv = (p < rend);
            const unsigned short* ar;
            if (GATHER) ar = sv ? A + (size_t)tok[p] * LDA : A;
            else        ar = sv ? A + (size_t)p * LDA      : A;
            agp[j][h] = ar + c * 8;
            bgp[j][h] = bbase + (size_t)(h * 128 + r) * KD + c * 8;
        }
    }
    int wbase = wave * 512;   // wave-uniform LDS short-offset within a round

    f32x4 acc[8][4];
#pragma unroll
    for (int m = 0; m < 8; m++)
#pragma unroll
        for (int n = 0; n < 4; n++) acc[m][n] = (f32x4){0.f, 0.f, 0.f, 0.f};

    bf16x8 af0[2], af1[2], bq[4][2];

// LDS layout (shorts): A: buf*16384 + h*8192 + j*4096 + slotpart; B: +32768
#define STAGE_A(buf, h, kt) do { int _k = ((kt) < KT ? (kt) : KT - 1) * 64;     \
    glds16(agp[0][h] + _k, &lds[(buf) * 16384 + (h) * 8192 + wbase]);           \
    glds16(agp[1][h] + _k, &lds[(buf) * 16384 + (h) * 8192 + 4096 + wbase]); } while (0)
#define STAGE_B(buf, h, kt) do { int _k = ((kt) < KT ? (kt) : KT - 1) * 64;     \
    glds16(bgp[0][h] + _k, &lds[32768 + (buf) * 16384 + (h) * 8192 + wbase]);   \
    glds16(bgp[1][h] + _k, &lds[32768 + (buf) * 16384 + (h) * 8192 + 4096 + wbase]); } while (0)

#define ALDS(buf, m, ks) (*(const bf16x8*)&lds[(buf) * 16384 +                  \
    (((m) * 32 + wm16 + l15) * 8 + ((((ks) * 4) + qq) ^ l7)) * 8])
#define BLDS(buf, n, ks) (*(const bf16x8*)&lds[32768 + (buf) * 16384 +          \
    (((n) * 64 + wn16 + l15) * 8 + ((((ks) * 4) + qq) ^ l7)) * 8])

#define PH_READA(buf, m0)                                                       \
    af0[0] = ALDS(buf, m0, 0); af0[1] = ALDS(buf, m0, 1);                       \
    af1[0] = ALDS(buf, (m0) + 1, 0); af1[1] = ALDS(buf, (m0) + 1, 1);
#define PH_READB(buf)                                                           \
    _Pragma("unroll") for (int n = 0; n < 4; n++) {                             \
        bq[n][0] = BLDS(buf, n, 0); bq[n][1] = BLDS(buf, n, 1); }

#define MFMA16(m0) do {                                                         \
    _Pragma("unroll") for (int n = 0; n < 4; n++) {                             \
        acc[m0][n] = __builtin_amdgcn_mfma_f32_16x16x32_bf16(af0[0], bq[n][0], acc[m0][n], 0, 0, 0);         \
        acc[m0][n] = __builtin_amdgcn_mfma_f32_16x16x32_bf16(af0[1], bq[n][1], acc[m0][n], 0, 0, 0);         \
        acc[(m0) + 1][n] = __builtin_amdgcn_mfma_f32_16x16x32_bf16(af1[0], bq[n][0], acc[(m0) + 1][n], 0, 0, 0); \
        acc[(m0) + 1][n] = __builtin_amdgcn_mfma_f32_16x16x32_bf16(af1[1], bq[n][1], acc[(m0) + 1][n], 0, 0, 0); } } while (0)

#define SYNCA(m0)                                                               \
    __builtin_amdgcn_sched_barrier(0);                                          \
    __builtin_amdgcn_s_barrier();                                               \
    asm volatile("s_waitcnt lgkmcnt(0)" ::: "memory");                          \
    __builtin_amdgcn_sched_barrier(0);                                          \
    __builtin_amdgcn_s_setprio(1);                                              \
    MFMA16(m0);                                                                 \
    __builtin_amdgcn_s_setprio(0);                                              \
    __builtin_amdgcn_sched_barrier(0);                                          \
    __builtin_amdgcn_s_barrier();

#define SYNCV(m0)                                                               \
    __builtin_amdgcn_sched_barrier(0);                                          \
    asm volatile("s_waitcnt vmcnt(6)" ::: "memory");                            \
    __builtin_amdgcn_s_barrier();                                               \
    asm volatile("s_waitcnt lgkmcnt(0)" ::: "memory");                          \
    __builtin_amdgcn_sched_barrier(0);                                          \
    __builtin_amdgcn_s_setprio(1);                                              \
    MFMA16(m0);                                                                 \
    __builtin_amdgcn_s_setprio(0);                                              \
    __builtin_amdgcn_sched_barrier(0);                                          \
    __builtin_amdgcn_s_barrier();

    // prologue: tile0 (4 halves) + tile1's Bh0,Bh1,Ah0; drain tile0, keep 3 in flight
    STAGE_A(0, 0, 0); STAGE_A(0, 1, 0); STAGE_B(0, 0, 0); STAGE_B(0, 1, 0);
    STAGE_B(1, 0, 1); STAGE_B(1, 1, 1); STAGE_A(1, 0, 1);
    __builtin_amdgcn_sched_barrier(0);
    asm volatile("s_waitcnt vmcnt(6)" ::: "memory");
    __builtin_amdgcn_s_barrier();
    __builtin_amdgcn_sched_barrier(0);

    for (int i = 0; i < KT / 2; i++) {
        int t1 = 2 * i + 1, t2 = 2 * i + 2, t3 = 2 * i + 3;
        PH_READB(0); PH_READA(0, 0); STAGE_A(1, 1, t1); SYNCA(0);   // p1
        PH_READA(0, 2);              STAGE_B(0, 0, t2); SYNCA(2);   // p2
        PH_READA(0, 4);              STAGE_B(0, 1, t2); SYNCA(4);   // p3
        PH_READA(0, 6);              STAGE_A(0, 0, t2); SYNCV(6);   // p4
        PH_READB(1); PH_READA(1, 0); STAGE_A(0, 1, t2); SYNCA(0);   // p5
        PH_READA(1, 2);              STAGE_B(1, 0, t3); SYNCA(2);   // p6
        PH_READA(1, 4);              STAGE_B(1, 1, t3); SYNCA(4);   // p7
        PH_READA(1, 6);              STAGE_A(1, 0, t3); SYNCV(6);   // p8
    }
    asm volatile("s_waitcnt vmcnt(0)" ::: "memory");   // retire leftover DMA

#undef STAGE_A
#undef STAGE_B
#undef ALDS
#undef BLDS
#undef PH_READA
#undef PH_READB
#undef MFMA16
#undef SYNCA
#undef SYNCV

#pragma unroll
    for (int m = 0; m < 8; m++) {
        int rbase = row0 + m * 32 + wm16 + qq * 4;
#pragma unroll
        for (int reg = 0; reg < 4; reg++) {
            int p = rbase + reg;
            if (p >= rend) continue;
            if (FUSE) {
#pragma unroll
                for (int n2 = 0; n2 < 2; n2++) {
                    float g = acc[m][2 * n2][reg];
                    float u = acc[m][2 * n2 + 1][reg];
                    float s = (g / (1.f + __expf(-g))) * u;
                    int col = ct * 128 + n2 * 64 + wn16 + l15;
                    C[(size_t)p * NC + col] = f2b(s);
                }
            } else {
#pragma unroll
                for (int n = 0; n < 4; n++) {
                    int col = ct * 256 + n * 64 + wn16 + l15;
                    C[(size_t)p * NC + col] = f2b(acc[m][n][reg]);
                }
            }
        }
    }
}

// ---------------- weighted gather combine ----------------

__global__ void combine_k(const unsigned short* __restrict__ outs,  // [NK][H] bf16
                          const int* __restrict__ inv,              // [NK]
                          const void* __restrict__ w,               // [N][K]
                          void* __restrict__ out,                   // [N][H]
                          const int* __restrict__ mode) {
    bool fp32m = (mode[0] != 0);
    int gid = blockIdx.x * 256 + threadIdx.x;   // N*H/8 threads
    int t  = gid >> 8;                          // H/8 = 256 chunks per token
    int c8 = (gid & 255) * 8;
    int p0 = inv[t * 2], p1 = inv[t * 2 + 1];
    float w0, w1;
    if (fp32m) {
        const float* wf = (const float*)w;
        w0 = wf[t * 2]; w1 = wf[t * 2 + 1];
    } else {
        const unsigned short* wu = (const unsigned short*)w;
        w0 = b2f(wu[t * 2]); w1 = b2f(wu[t * 2 + 1]);
    }
    uint4 v0 = *(const uint4*)(outs + (size_t)p0 * HD + c8);
    uint4 v1 = *(const uint4*)(outs + (size_t)p1 * HD + c8);
    const unsigned short* a = (const unsigned short*)&v0;
    const unsigned short* b = (const unsigned short*)&v1;
    float r[8];
    for (int i = 0; i < 8; i++) r[i] = w0 * b2f(a[i]) + w1 * b2f(b[i]);
    if (fp32m) {
        float* of = (float*)out + (size_t)t * HD + c8;
        *(float4*)of       = make_float4(r[0], r[1], r[2], r[3]);
        *(float4*)(of + 4) = make_float4(r[4], r[5], r[6], r[7]);
    } else {
        uint4 o;
        unsigned int* ro = (unsigned int*)&o;
        for (int i = 0; i < 4; i++)
            ro[i] = f2b(r[2 * i]) | ((unsigned int)f2b(r[2 * i + 1]) << 16);
        *(uint4*)((unsigned short*)out + (size_t)t * HD + c8) = o;
    }
}

// ---------------- launch ----------------

extern "C" void kernel_launch(void* const* d_in, const int* in_sizes, int n_in,
                              void* d_out, int out_size, void* d_ws, size_t ws_size,
                              hipStream_t stream) {
    const void* x   = d_in[0];                 // [N][H] fp32 or bf16
    const int*  idx = (const int*)d_in[1];     // [N][K] i32
    const void* w   = d_in[2];                 // [N][K] fp32 or bf16
    const void* gup = d_in[3];                 // [E][H][2I]
    const void* dwn = d_in[4];                 // [E][I][H]

    char* ws = (char*)d_ws;
    int* mode = (int*)(ws);
    int* cnt  = (int*)(ws + 64);
    int* base = (int*)(ws + 128);              // 9 ints
    int* fill = (int*)(ws + 192);
    int* tb   = (int*)(ws + 256);              // 9 ints (256-row tile prefix)
    int* tok  = (int*)(ws + 512);
    int* inv  = (int*)(ws + 512 + 4 * NK);
    // big arrays (shorts); outs aliases gupT (dead after gemm1). total ~218 MB.
    unsigned short* inter = (unsigned short*)(ws + 262144);          // [NK][I]
    unsigned short* xb    = inter + (size_t)NK * ID;                 // [N][H]
    unsigned short* dwnT  = xb    + (size_t)N_TOK * HD;              // [E][H][I]
    unsigned short* gupT  = dwnT  + (size_t)NEXP * HD * ID;          // [E][2I][H] ilv
    unsigned short* outs  = gupT;                                    // [NK][H] alias

    static bool attr_done = false;
    if (!attr_done) {
        hipFuncSetAttribute(
            reinterpret_cast<const void*>(&gemm8_k<HD, 2 * ID, HD, true, true>),
            hipFuncAttributeMaxDynamicSharedMemorySize, 131072);
        hipFuncSetAttribute(
            reinterpret_cast<const void*>(&gemm8_k<ID, HD, ID, false, false>),
            hipFuncAttributeMaxDynamicSharedMemorySize, 131072);
        attr_done = true;
    }

    probe_k<<<1, 1024, 0, stream>>>((const unsigned short*)x, mode);
    convert_x<<<(N_TOK * HD / 8) / 256, 256, 0, stream>>>(x, xb, mode);

    init_k<<<1, 64, 0, stream>>>(cnt, fill);
    route_count<<<NK / 256, 256, 0, stream>>>(idx, cnt);
    route_scan<<<1, 64, 0, stream>>>(cnt, base, tb);
    route_scatter<<<NK / 256, 256, 0, stream>>>(idx, base, fill, tok, inv);

    transpose_k<<<dim3(2 * ID / 64, HD / 64, NEXP), 256, 0, stream>>>(
        gup, gupT, HD, 2 * ID, 1, mode);      // interleaved gate64|up64
    transpose_k<<<dim3(HD / 64, ID / 64, NEXP), 256, 0, stream>>>(
        dwn, dwnT, ID, HD, 0, mode);

    // gemm1 (+fused SwiGLU): inter[NK][1408] = swiglu(xb @ gupT)
    gemm8_k<HD, 2 * ID, HD, true, true>
        <<<NT256 * (2 * ID / 256), 512, 131072, stream>>>(xb, gupT, base, tb, tok, inter);
    // gemm2: outs[NK][2048] = inter @ dwnT
    gemm8_k<ID, HD, ID, false, false>
        <<<NT256 * (HD / 256), 512, 131072, stream>>>(inter, dwnT, base, tb, tok, outs);

    combine_k<<<(N_TOK * HD / 8) / 256, 256, 0, stream>>>(outs, inv, w, d_out, mode);
}